// Round 1
// baseline (216.869 us; speedup 1.0000x reference)
//
#include <hip/hip_runtime.h>
#include <hip/hip_bf16.h>
#include <stdint.h>

typedef __bf16 bf16;
typedef bf16 bf16x4 __attribute__((ext_vector_type(4)));
typedef bf16 bf16x8 __attribute__((ext_vector_type(8)));
typedef float f32x4 __attribute__((ext_vector_type(4)));

#define LOGSQRT2PI 0.9189385332046727f

__device__ __forceinline__ void gload_lds16(const void* g, void* l) {
    __builtin_amdgcn_global_load_lds((__attribute__((address_space(1))) void*)g,
                                     (__attribute__((address_space(3))) void*)l,
                                     16, 0, 0);
}

// ---- zero the two scalar accumulators in d_out ----
__global__ void k_zero2(float* p) {
    if (threadIdx.x < 2) p[threadIdx.x] = 0.0f;
}

// ---- weight prep: W = mu + (1e-6+softplus(p))*eps ; write Wt[n][k] bf16 ;
// ---- accumulate lqw/lpw into osc[0]/osc[1] ----
__global__ void k_prep(const float* __restrict__ mu, const float* __restrict__ p,
                       const float* __restrict__ eps, bf16* __restrict__ Wt,
                       int K, int N, int Npad, float* __restrict__ osc) {
    int total = K * Npad;
    float lqw = 0.0f, lpw = 0.0f;
    for (int idx = blockIdx.x * blockDim.x + threadIdx.x; idx < total;
         idx += gridDim.x * blockDim.x) {
        int k = idx / Npad;
        int n = idx - k * Npad;
        float w = 0.0f;
        if (n < N) {
            int src = k * N + n;
            float m = mu[src];
            float e = eps[src];
            float sd = 1e-6f + log1pf(expf(p[src]));
            w = m + sd * e;
            float z = (w - m) / sd;   // == eps up to fp32 rounding (match reference)
            lqw += -LOGSQRT2PI - logf(sd) - 0.5f * z * z;
            lpw += -LOGSQRT2PI - 0.5f * w * w;
        }
        Wt[n * K + k] = (bf16)w;      // transposed store: Wt is [Npad][K]
    }
    // wave reduce (64 lanes)
    #pragma unroll
    for (int off = 32; off; off >>= 1) {
        lqw += __shfl_down(lqw, off);
        lpw += __shfl_down(lpw, off);
    }
    if ((threadIdx.x & 63) == 0) {
        atomicAdd(&osc[0], lqw);
        atomicAdd(&osc[1], lpw);
    }
}

// ---- x fp32 -> bf16 ----
__global__ void k_cvt(const float4* __restrict__ in, bf16x4* __restrict__ out, int n4) {
    int stride = gridDim.x * blockDim.x;
    for (int i = blockIdx.x * blockDim.x + threadIdx.x; i < n4; i += stride) {
        float4 v = in[i];
        bf16x4 o;
        o[0] = (bf16)v.x; o[1] = (bf16)v.y; o[2] = (bf16)v.z; o[3] = (bf16)v.w;
        out[i] = o;
    }
}

// ---- 128x128 tile GEMM: C[M][N] = A[M][K] @ Bt[N][K]^T, bf16 in/out, optional ReLU ----
template<bool RELU>
__global__ __launch_bounds__(256, 2)
void k_gemm128(const bf16* __restrict__ A, const bf16* __restrict__ Bt,
               bf16* __restrict__ C, int M, int N, int K) {
    __shared__ bf16 As[128 * 32];
    __shared__ bf16 Bs[128 * 32];
    const int tid  = threadIdx.x;
    const int lane = tid & 63;
    const int wave = tid >> 6;
    const int wr = (wave >> 1) * 64;
    const int wc = (wave & 1) * 64;
    const long bm = (long)blockIdx.x * 128;
    const long bn = (long)blockIdx.y * 128;

    // staging: thread t loads chunks t and t+256 (8 bf16 = 16B each), row = chunk/4
    const bf16* ag0 = A  + (bm + (tid >> 2)) * K + (tid & 3) * 8;
    const bf16* ag1 = ag0 + (long)64 * K;
    const bf16* bg0 = Bt + (bn + (tid >> 2)) * K + (tid & 3) * 8;
    const bf16* bg1 = bg0 + (long)64 * K;
    bf16* al0 = &As[tid * 8];
    bf16* al1 = &As[2048 + tid * 8];
    bf16* bl0 = &Bs[tid * 8];
    bf16* bl1 = &Bs[2048 + tid * 8];

    f32x4 acc[4][4];
    #pragma unroll
    for (int i = 0; i < 4; i++)
        #pragma unroll
        for (int j = 0; j < 4; j++) acc[i][j] = (f32x4){0.f, 0.f, 0.f, 0.f};

    const int r  = lane & 15;
    const int kh = (lane >> 4) * 8;

    for (int kt = 0; kt < K; kt += 32) {
        gload_lds16(ag0 + kt, al0);
        gload_lds16(ag1 + kt, al1);
        gload_lds16(bg0 + kt, bl0);
        gload_lds16(bg1 + kt, bl1);
        __syncthreads();   // drains vmcnt before barrier (compiler-inserted)
        bf16x8 a[4], b[4];
        #pragma unroll
        for (int i = 0; i < 4; i++)
            a[i] = *(const bf16x8*)&As[(wr + i * 16 + r) * 32 + kh];
        #pragma unroll
        for (int j = 0; j < 4; j++)
            b[j] = *(const bf16x8*)&Bs[(wc + j * 16 + r) * 32 + kh];
        #pragma unroll
        for (int i = 0; i < 4; i++)
            #pragma unroll
            for (int j = 0; j < 4; j++)
                acc[i][j] = __builtin_amdgcn_mfma_f32_16x16x32_bf16(a[i], b[j], acc[i][j], 0, 0, 0);
        __syncthreads();
    }

    // epilogue: C/D layout col = lane&15, row = (lane>>4)*4 + q
    #pragma unroll
    for (int i = 0; i < 4; i++) {
        #pragma unroll
        for (int j = 0; j < 4; j++) {
            #pragma unroll
            for (int q = 0; q < 4; q++) {
                long row = bm + wr + i * 16 + (lane >> 4) * 4 + q;
                long col = bn + wc + j * 16 + (lane & 15);
                float v = acc[i][j][q];
                if (RELU) v = fmaxf(v, 0.0f);
                C[row * N + col] = (bf16)v;
            }
        }
    }
}

// ---- final layer: C[M][10] fp32 = A[M][512] @ Bt[16][512]^T (cols 10..15 are zero-pad) ----
__global__ __launch_bounds__(256)
void k_gemm_out(const bf16* __restrict__ A, const bf16* __restrict__ Bt,
                float* __restrict__ C) {
    __shared__ bf16 Bs[16 * 520];   // +8 elem row pad -> 2-way conflicts only
    const int tid = threadIdx.x;
    #pragma unroll
    for (int c = tid; c < 1024; c += 256) {   // 1024 chunks of 8 bf16
        int n = c >> 6;           // c*8/512
        int k = (c & 63) * 8;
        *(bf16x8*)&Bs[n * 520 + k] = *(const bf16x8*)&Bt[n * 512 + k];
    }
    __syncthreads();
    const int lane = tid & 63, wave = tid >> 6;
    const long m0 = (long)blockIdx.x * 64 + wave * 16;
    const int r  = lane & 15;
    const int kh = (lane >> 4) * 8;
    const bf16* ap = A + (m0 + r) * 512 + kh;
    f32x4 acc = (f32x4){0.f, 0.f, 0.f, 0.f};
    #pragma unroll
    for (int kt = 0; kt < 512; kt += 32) {
        bf16x8 a = *(const bf16x8*)(ap + kt);
        bf16x8 b = *(const bf16x8*)&Bs[r * 520 + kt + kh];
        acc = __builtin_amdgcn_mfma_f32_16x16x32_bf16(a, b, acc, 0, 0, 0);
    }
    if (r < 10) {
        #pragma unroll
        for (int q = 0; q < 4; q++) {
            long row = m0 + (lane >> 4) * 4 + q;
            C[row * 10 + r] = acc[q];
        }
    }
}

extern "C" void kernel_launch(void* const* d_in, const int* in_sizes, int n_in,
                              void* d_out, int out_size, void* d_ws, size_t ws_size,
                              hipStream_t stream) {
    const float* x   = (const float*)d_in[0];
    const float* mu1 = (const float*)d_in[1];
    const float* p1  = (const float*)d_in[2];
    const float* e1  = (const float*)d_in[3];
    const float* mu2 = (const float*)d_in[4];
    const float* p2  = (const float*)d_in[5];
    const float* e2  = (const float*)d_in[6];
    const float* mu3 = (const float*)d_in[7];
    const float* p3  = (const float*)d_in[8];
    const float* e3  = (const float*)d_in[9];
    float* out = (float*)d_out;

    const int B = 65536, D = 512, DO = 10, DOP = 16;

    // workspace layout (bytes):
    //   Wt1: [512][512] bf16 @ 0         (512 KB)
    //   Wt2: [512][512] bf16 @ 524288    (512 KB)
    //   Wt3: [16][512]  bf16 @ 1048576   (16 KB)
    //   xb : [B][512]   bf16 @ 1114112   (64 MB)   -- reused as h2 after GEMM1
    //   h1 : [B][512]   bf16 @ 1114112+64MB (64 MB)
    char* ws = (char*)d_ws;
    bf16* Wt1 = (bf16*)(ws);
    bf16* Wt2 = (bf16*)(ws + 524288);
    bf16* Wt3 = (bf16*)(ws + 1048576);
    bf16* xb  = (bf16*)(ws + 1114112);
    bf16* h1  = (bf16*)(ws + 1114112 + 67108864);
    bf16* h2  = xb;   // x no longer needed once GEMM1 is done

    float* osc = out + (long)B * DO;   // out[655360], out[655361]

    hipLaunchKernelGGL(k_zero2, dim3(1), dim3(64), 0, stream, osc);
    hipLaunchKernelGGL(k_prep, dim3(256), dim3(256), 0, stream, mu1, p1, e1, Wt1, D, D,  D,   osc);
    hipLaunchKernelGGL(k_prep, dim3(256), dim3(256), 0, stream, mu2, p2, e2, Wt2, D, D,  D,   osc);
    hipLaunchKernelGGL(k_prep, dim3(16),  dim3(256), 0, stream, mu3, p3, e3, Wt3, D, DO, DOP, osc);
    hipLaunchKernelGGL(k_cvt, dim3(2048), dim3(256), 0, stream,
                       (const float4*)x, (bf16x4*)xb, B * D / 4);
    hipLaunchKernelGGL((k_gemm128<true>), dim3(B / 128, D / 128), dim3(256), 0, stream,
                       xb, Wt1, h1, B, D, D);
    hipLaunchKernelGGL((k_gemm128<true>), dim3(B / 128, D / 128), dim3(256), 0, stream,
                       h1, Wt2, h2, B, D, D);
    hipLaunchKernelGGL(k_gemm_out, dim3(B / 64), dim3(256), 0, stream, h2, Wt3, out);
}